// Round 4
// baseline (359.468 us; speedup 1.0000x reference)
//
#include <hip/hip_runtime.h>
#include <hip/hip_bf16.h>

// Problem constants
#define B_   32
#define C_   128
#define H_   56
#define W_   56
#define KSEL 2
#define E_   8
#define KN_  128
// KS=3, PAD=1

typedef __attribute__((ext_vector_type(8))) short short8;   // 8 x bf16
typedef __attribute__((ext_vector_type(4))) float f32x4;    // MFMA accumulator

static __device__ __forceinline__ ushort f2bf(float f) {
  union { float f; uint u; } v; v.f = f;
  uint u = v.u;
  return (ushort)((u + 0x7fffu + ((u >> 16) & 1u)) >> 16);  // RNE
}

// xh layout (A-fragment-contiguous): [b][cc(4)][hp(58)][cell(58)][32c] bf16.
//   cell = 64 B (no pad). A wave's A-frag read (16 cells x 64B) is one
//   contiguous 1KB coalesced load. Halo rows/cells zero.
#define CELL_US 32
#define ROW_US  1856          // 58 cells * 32 us = 3712 B
#define PLANE_US (58 * ROW_US) // one cc plane of one b

// ---------------------------------------------------------------------------
// Kernel 0: x fp32 NCHW -> bf16 cc-plane layout with zero halo.
// grid = (58, 32) blocks x 256 threads. Transpose via LDS.
// ---------------------------------------------------------------------------
__global__ __launch_bounds__(256) void prep_x_kernel(
    const float* __restrict__ x, ushort* __restrict__ xh) {
  const int hp = blockIdx.x;   // 0..57
  const int b  = blockIdx.y;
  const int tid = threadIdx.x;

  if (hp == 0 || hp == 57) {            // zero halo rows (all 4 cc planes)
    uint4 z = make_uint4(0, 0, 0, 0);
#pragma unroll
    for (int cc = 0; cc < 4; ++cc) {
      ushort* rp = xh + (size_t)(b * 4 + cc) * PLANE_US + (size_t)hp * ROW_US;
      for (int l = tid; l < 232; l += 256) ((uint4*)rp)[l] = z;
    }
    return;
  }
  const int h = hp - 1;
  __shared__ __align__(16) ushort sT[56 * 136];   // [w][c], c-stride padded

  const float* xb = x + (size_t)b * C_ * H_ * W_ + h * W_;
#pragma unroll
  for (int it = 0; it < 7; ++it) {
    int i4 = tid + it * 256;            // 0..1791
    int c  = i4 / 14;
    int w4 = (i4 - c * 14) * 4;
    float4 v = *(const float4*)(xb + (size_t)c * (H_ * W_) + w4);
    sT[(w4 + 0) * 136 + c] = f2bf(v.x);
    sT[(w4 + 1) * 136 + c] = f2bf(v.y);
    sT[(w4 + 2) * 136 + c] = f2bf(v.z);
    sT[(w4 + 3) * 136 + c] = f2bf(v.w);
  }
  __syncthreads();
  // write 4 cc-plane rows: 4cc x 58 cells x 4 uint4 = 928 chunks
  for (int q = tid; q < 928; q += 256) {
    int cc   = q / 232, rem = q - cc * 232;
    int cell = rem >> 2, sub = rem & 3;
    uint4 v = make_uint4(0, 0, 0, 0);
    if (cell >= 1 && cell <= 56)
      v = *(const uint4*)&sT[(cell - 1) * 136 + cc * 32 + sub * 8];
    ushort* rp = xh + (size_t)(b * 4 + cc) * PLANE_US + (size_t)hp * ROW_US;
    *(uint4*)(rp + cell * CELL_US + sub * 8) = v;
  }
}

// ---------------------------------------------------------------------------
// Kernel 1: fuse 1x1 mix into 3x3 weights (fp32 tiled GEMM), emit bf16 in
// MFMA B-fragment-tiled layout:
//   Weff2[e][j][nt(8)][ct(4)][lane(64)][8]  (ushort)  (unchanged)
// ---------------------------------------------------------------------------
__global__ __launch_bounds__(256) void fuse_weights_kernel(
    const float* __restrict__ Ws,    // [E][KN][C][9]
    const float* __restrict__ Wch,   // [E][C][256]
    ushort* __restrict__ Weff) {     // tiled bf16, see above
  const int e  = blockIdx.x;
  const int o0 = blockIdx.y * 32;
  const int c0 = blockIdx.z * 32;
  const int tid = threadIdx.x;
  const int ol = tid >> 3;           // 0..31
  const int cq = (tid & 7) * 4;      // 0..28

  __shared__ __align__(16) float sA[32 * 129];       // Wch gate part [o][k]
  __shared__ __align__(16) float sB[32 * 32 * 12];   // Ws chunk [k][c][12]

#pragma unroll
  for (int it = 0; it < 4; ++it) {
    int i4 = tid + it * 256;         // 0..1023
    int o  = i4 >> 5;                // 0..31
    int kk = (i4 & 31) * 4;          // 0..124
    float4 v = *(const float4*)(Wch + (size_t)(e * C_ + o0 + o) * 256 + 128 + kk);
    sA[o * 129 + kk + 0] = v.x;
    sA[o * 129 + kk + 1] = v.y;
    sA[o * 129 + kk + 2] = v.z;
    sA[o * 129 + kk + 3] = v.w;
  }

  float acc[9][4];
#pragma unroll
  for (int j = 0; j < 9; ++j)
#pragma unroll
    for (int c2 = 0; c2 < 4; ++c2) acc[j][c2] = 0.f;

  for (int k0 = 0; k0 < 128; k0 += 32) {
    __syncthreads();
    {  // stage sB: 32 k-rows, each 288 contiguous floats (32c x 9j), repack [k][c][12]
      int k = tid >> 3, seg = tid & 7;
      const float* src = Ws + ((size_t)(e * KN_ + k0 + k) * C_ + c0) * 9 + seg * 36;
      float vb[36];
#pragma unroll
      for (int q = 0; q < 9; ++q) {
        float4 v = *(const float4*)(src + q * 4);
        vb[q * 4 + 0] = v.x; vb[q * 4 + 1] = v.y;
        vb[q * 4 + 2] = v.z; vb[q * 4 + 3] = v.w;
      }
      int c = seg * 4, j = 0;   // seg*36 = (seg*4)*9 exactly
#pragma unroll
      for (int m = 0; m < 36; ++m) {
        sB[(k * 32 + c) * 12 + j] = vb[m];
        if (++j == 9) { j = 0; ++c; }
      }
    }
    __syncthreads();
    for (int k = 0; k < 32; ++k) {
      float a = sA[ol * 129 + k0 + k];
#pragma unroll
      for (int c2 = 0; c2 < 4; ++c2) {
        const float* bp = &sB[(k * 32 + cq + c2) * 12];
#pragma unroll
        for (int j = 0; j < 9; ++j) acc[j][c2] += a * bp[j];
      }
    }
  }

  const int o = o0 + ol;
#pragma unroll
  for (int c2 = 0; c2 < 4; ++c2)
    acc[4][c2] += Wch[(size_t)(e * C_ + o) * 256 + c0 + cq + c2];

  const int nt   = (o0 >> 4) + (ol >> 4);
  const int lane = ((cq >> 3) << 4) | (ol & 15);
#pragma unroll
  for (int j = 0; j < 9; ++j) {
    uint lo = (uint)f2bf(acc[j][0]) | ((uint)f2bf(acc[j][1]) << 16);
    uint hi = (uint)f2bf(acc[j][2]) | ((uint)f2bf(acc[j][3]) << 16);
    size_t base = ((((size_t)(e * 9 + j) * 8 + nt) * 4 + blockIdx.z) * 64 + lane) * 8
                  + (cq & 4);
    *(uint2*)(Weff + base) = make_uint2(lo, hi);
  }
}

// ---------------------------------------------------------------------------
// Kernel 2: implicit-GEMM MFMA conv, ZERO-LDS main loop.
// A-fragments read directly from L2-resident xh (contiguous 1KB wave loads,
// identical addresses for nh-paired waves -> L1 hits, 15/16 L1 reuse across
// dx). B-fragments direct from L2-resident fragment-tiled Weff. No barriers,
// no staging; LDS used only by the store epilogue. 3 blocks/CU.
// ---------------------------------------------------------------------------
#define OSTR 228   // f32 epilogue o-stride (224 + 4 pad)

__global__ __launch_bounds__(256, 3) void conv_mfma_kernel(
    const ushort* __restrict__ xh,   // cc-plane layout, see prep
    const int* __restrict__ gate,    // [B][KSEL]
    const ushort* __restrict__ Weff, // fragment-tiled bf16
    float* __restrict__ out) {       // [B][KSEL][C][H][W] fp32
  // --- swizzled block mapping: XCD = P%8 gets b in [4*xcd, 4*xcd+4) ---
  const int P   = blockIdx.x;        // 0..895
  const int xcd = P & 7;
  const int s   = P >> 3;            // 0..111
  const int bl  = s / 28;
  const int r1  = s - bl * 28;
  const int g   = r1 / 14;
  const int ht  = r1 - g * 14;       // 0..13
  const int b   = xcd * 4 + bl;
  const int bg  = b * 2 + g;
  const int h0  = ht * 4;
  const int e   = gate[bg];

  const int tid = threadIdx.x;
  const int wv = tid >> 6, lane = tid & 63;
  const int l15 = lane & 15, kq = lane >> 4;
  const int mh = wv >> 1, nh = wv & 1;

  __shared__ __align__(16) float sO[32 * OSTR];   // 29184 B, epilogue only

  f32x4 acc[7][4];
#pragma unroll
  for (int t = 0; t < 7; ++t)
#pragma unroll
    for (int i = 0; i < 4; ++i) acc[t][i] = (f32x4){0.f, 0.f, 0.f, 0.f};

  // per-lane A offsets (ushort units) within one cc plane, at dy=dx=0
  int aoff[7];
#pragma unroll
  for (int t = 0; t < 7; ++t) {
    int p = mh * 112 + t * 16 + l15;   // 0..223
    int r = p / 56;
    int w = p - r * 56;
    aoff[t] = (h0 + r) * ROW_US + w * CELL_US + kq * 8;
  }

  const ushort* xb = xh + (size_t)(b * 4) * PLANE_US;
  //   Weff offset(e,j,nt,ct,lane) = ((((e*9+j)*8+nt)*4+ct)*64+lane)*8 ushorts
  const ushort* wlane = Weff + (size_t)e * (9 * 8 * 4 * 64 * 8)
                             + (size_t)(nh * 4) * (4 * 64 * 8)
                             + (size_t)lane * 8;

  for (int cc = 0; cc < 4; ++cc) {
    const ushort* xcc = xb + (size_t)cc * PLANE_US;
    const ushort* wcc = wlane + cc * (64 * 8);
#pragma unroll
    for (int dy = 0; dy < 3; ++dy) {
#pragma unroll
      for (int dx = 0; dx < 3; ++dx) {
        const int j = dy * 3 + dx;
        short8 bfr[4];
#pragma unroll
        for (int i = 0; i < 4; ++i)
          bfr[i] = *(const short8*)(wcc + (size_t)j * (8 * 4 * 64 * 8)
                                        + (size_t)i * (4 * 64 * 8));
        const int ao = dy * ROW_US + dx * CELL_US;
#pragma unroll
        for (int t = 0; t < 7; ++t) {
          short8 a = *(const short8*)(xcc + aoff[t] + ao);
#pragma unroll
          for (int i = 0; i < 4; ++i)
            acc[t][i] = __builtin_amdgcn_mfma_f32_16x16x32_bf16(a, bfr[i], acc[t][i], 0, 0, 0);
        }
      }
    }
  }

  // -------- LDS-transposed epilogue: 4 groups of 32 o --------
  for (int gq = 0; gq < 4; ++gq) {
    if (nh == (gq >> 1)) {
      const int gg = gq & 1;
#pragma unroll
      for (int ii = 0; ii < 2; ++ii) {
        const int i = gg * 2 + ii;
#pragma unroll
        for (int t = 0; t < 7; ++t) {
          int p0 = mh * 112 + t * 16 + kq * 4;
          int r  = p0 / 56;
          int w0 = p0 - r * 56;
          *(float4*)&sO[(ii * 16 + l15) * OSTR + r * 56 + w0] =
              make_float4(acc[t][i][0], acc[t][i][1], acc[t][i][2], acc[t][i][3]);
        }
      }
    }
    __syncthreads();   // staged data visible
    {
      float* ob = out + ((size_t)bg * C_ + 32 * gq) * (H_ * W_) + (size_t)h0 * W_;
#pragma unroll
      for (int k = 0; k < 7; ++k) {
        int idx = k * 256 + tid;        // 0..1791
        int ol  = idx / 56;
        int pos = idx - ol * 56;
        float4 v = *(const float4*)&sO[ol * OSTR + pos * 4];
        *(float4*)(ob + (size_t)ol * (H_ * W_) + pos * 4) = v;
      }
    }
    __syncthreads();   // write-out reads done before next group staging
  }
}

extern "C" void kernel_launch(void* const* d_in, const int* in_sizes, int n_in,
                              void* d_out, int out_size, void* d_ws, size_t ws_size,
                              hipStream_t stream) {
  const float* x    = (const float*)d_in[0];   // [32,128,56,56]
  const int*   gate = (const int*)d_in[1];     // [32,2]
  const float* Ws   = (const float*)d_in[2];   // [8,128,128,3,3]
  const float* Wch  = (const float*)d_in[3];   // [8,128,256,1,1]
  float* out = (float*)d_out;                  // [32,2,128,56,56]

  ushort* xh   = (ushort*)d_ws;                       // 32*4*58*58*32 us = 27.56 MB
  ushort* Weff = xh + (size_t)(32 * 4) * PLANE_US;    // [8][9][8][4][64][8] bf16 = 2.36 MB

  dim3 g0(58, 32);
  prep_x_kernel<<<g0, 256, 0, stream>>>(x, xh);

  dim3 g1(8, 4, 4);
  fuse_weights_kernel<<<g1, 256, 0, stream>>>(Ws, Wch, Weff);

  dim3 g2(896);
  conv_mfma_kernel<<<g2, 256, 0, stream>>>(xh, gate, Weff, out);
}